// Round 12
// baseline (235.623 us; speedup 1.0000x reference)
//
#include <hip/hip_runtime.h>
#include <stdint.h>
#include <stddef.h>

#define BB 4
#define TT 2048
#define DD 1024
#define HH 16
#define HDIM 64
#define BT (BB*TT)      // 8192 tokens
#define N1 (3*DD)       // 3072

typedef __attribute__((ext_vector_type(8))) short short8;
typedef __attribute__((ext_vector_type(4))) float floatx4;
typedef __attribute__((ext_vector_type(4))) unsigned short ushortx4;
typedef __attribute__((ext_vector_type(2))) unsigned int uint2v;

// fp32 -> bf16, round-to-nearest-even (scalar path)
__device__ __forceinline__ unsigned short f2b(float f) {
    unsigned int u = __float_as_uint(f);
    u += 0x7fffu + ((u >> 16) & 1u);
    return (unsigned short)(u >> 16);
}

// HW packed fp32x2 -> bf16x2 (gfx950 v_cvt_pk_bf16_f32, RNE). low16=a, high16=b.
__device__ __forceinline__ unsigned int cvtpk(float a, float b) {
    unsigned int r;
    asm("v_cvt_pk_bf16_f32 %0, %1, %2" : "=v"(r) : "v"(a), "v"(b));
    return r;
}

// async global->LDS, 16B per lane; dest is wave-uniform base + lane*16
__device__ __forceinline__ void gld_lds16(const void* g, void* l) {
    __builtin_amdgcn_global_load_lds(
        (__attribute__((address_space(1))) void*)(g),
        (__attribute__((address_space(3))) void*)(l), 16, 0, 0);
}

// ---------------------------------------------------------------------------
// Fused prep: one launch replaces {cvt_bf16, transpose_cvt x2}.
//   blocks [0, 2048)        : x fp32 -> bf16, 16 floats/thread
//   blocks [2048, 5120)     : w_qkv [1024][3072] -> wqT [3072][1024] bf16
//   blocks [5120, 6144)     : w_out [1024][1024] -> woT [1024][1024] bf16
// ---------------------------------------------------------------------------
__global__ __launch_bounds__(256)
void prep(const float* __restrict__ x, unsigned short* __restrict__ xb,
          const float* __restrict__ w_qkv, unsigned short* __restrict__ wqT,
          const float* __restrict__ w_out, unsigned short* __restrict__ woT) {
    __shared__ float tile[32][33];
    const int bid = blockIdx.x;
    const int tid = threadIdx.x;
    if (bid < 2048) {
        const floatx4* src = (const floatx4*)x;
        ushortx4* dst = (ushortx4*)xb;
        const int base = bid * 1024 + tid;   // float4 units
        #pragma unroll
        for (int it = 0; it < 4; ++it) {
            const int i = base + it * 256;
            floatx4 f = src[i];
            ushortx4 o;
            o.x = f2b(f.x); o.y = f2b(f.y); o.z = f2b(f.z); o.w = f2b(f.w);
            dst[i] = o;
        }
        return;
    }
    const float* src;
    unsigned short* dst;
    int R, C, cx, ry;
    if (bid < 5120) {
        const int t = bid - 2048;
        cx = t % 96; ry = t / 96; src = w_qkv; dst = wqT; R = DD; C = N1;
    } else {
        const int t = bid - 5120;
        cx = t & 31; ry = t >> 5; src = w_out; dst = woT; R = DD; C = DD;
    }
    const int c0 = cx * 32, r0 = ry * 32;
    const int xx = tid & 31, y0 = tid >> 5;
    for (int yy = y0; yy < 32; yy += 8)
        tile[yy][xx] = src[(size_t)(r0 + yy) * C + c0 + xx];
    __syncthreads();
    for (int yy = y0; yy < 32; yy += 8)
        dst[(size_t)(c0 + yy) * R + r0 + xx] = f2b(tile[xx][yy]);
}

// ---------------------------------------------------------------------------
// QKV GEMM — R12: tile 128x192 (was 256x192), wave tile 64x96 (acc[4][6]),
// LDS 40 KB dbuf -> 3 blocks/CU (launch_bounds(256,3)): a THIRD independent
// barrier domain per CU to fill the ~47% stall cycles R11's counters showed
// (MfmaUtil 31 + VALUBusy 22; XCD swizzle halved FETCH with zero time delta
// -> not memory-bound, barrier-bound). Grid (16,64) = 1024 blocks = 4x256.
// XCD swizzle: swz=(lin&7)*128+(lin>>3); each XCD serves 8 row-panels
// (2 MB A, L2-resident). Datapath identical to the proven R1 structure.
// Epilogue: cols [0,1024) bf16*qscale, [1024,2048) bf16, [2048,3072)
// written transposed to vt as [bh*64+d][T] bf16 (packed via v_cvt_pk).
// ---------------------------------------------------------------------------
__global__ __launch_bounds__(256, 3)
void gemm_qkv(const unsigned short* __restrict__ A,
              const unsigned short* __restrict__ Bt,
              unsigned short* __restrict__ Cout, int M, int N, int K,
              float qscale, unsigned short* __restrict__ vt_out) {
    __shared__ unsigned short a_tile[2][128 * 32];   // 8 KB/buf
    __shared__ unsigned short b_tile[2][192 * 32];   // 12 KB/buf
    const int tid  = threadIdx.x;
    const int wave = tid >> 6;
    const int lane = tid & 63;
    const int quad = lane >> 4;
    const int lc   = lane & 15;
    const int wm = wave >> 1, wn = wave & 1;   // wave tile: rows wm*64, cols wn*96
    // XCD-aware remap: XCD k (lin%8==k) handles row-panels [8k, 8k+8)
    const int lin = blockIdx.y * 16 + blockIdx.x;
    const int swz = (lin & 7) * 128 + (lin >> 3);
    const int row0 = (swz >> 4) * 128;
    const int col0 = (swz & 15) * 192;

    // staging: chunks of 16 rows x 32 cols (1024 B = one wave gld_lds16).
    // A: 8 chunks, wave does {w, w+4}; B: 12 chunks, {w, w+4, w+8}.
    const int r_in = lane >> 2;
    const int kseg = (lane & 3) * 8;
    const unsigned short* gA0 = A  + (size_t)(row0 + (wave     ) * 16 + r_in) * K + kseg;
    const unsigned short* gA1 = A  + (size_t)(row0 + (wave +  4) * 16 + r_in) * K + kseg;
    const unsigned short* gB0 = Bt + (size_t)(col0 + (wave     ) * 16 + r_in) * K + kseg;
    const unsigned short* gB1 = Bt + (size_t)(col0 + (wave +  4) * 16 + r_in) * K + kseg;
    const unsigned short* gB2 = Bt + (size_t)(col0 + (wave +  8) * 16 + r_in) * K + kseg;
    const int sA0 = (wave     ) * 512, sA1 = (wave +  4) * 512;
    const int sA2 = (wave +  8) * 512;

    floatx4 acc[4][6];
    #pragma unroll
    for (int i = 0; i < 4; i++)
        #pragma unroll
        for (int j = 0; j < 6; j++)
            acc[i][j] = (floatx4){0.f, 0.f, 0.f, 0.f};

    gld_lds16(gA0, &a_tile[0][sA0]);
    gld_lds16(gA1, &a_tile[0][sA1]);
    gld_lds16(gB0, &b_tile[0][sA0]);
    gld_lds16(gB1, &b_tile[0][sA1]);
    gld_lds16(gB2, &b_tile[0][sA2]);
    int buf = 0;

    const int nkt = K >> 5;
    for (int kt = 0; kt < nkt; ++kt) {
        __syncthreads();
        if (kt + 1 < nkt) {
            gA0 += 32; gA1 += 32;
            gB0 += 32; gB1 += 32; gB2 += 32;
            gld_lds16(gA0, &a_tile[buf ^ 1][sA0]);
            gld_lds16(gA1, &a_tile[buf ^ 1][sA1]);
            gld_lds16(gB0, &b_tile[buf ^ 1][sA0]);
            gld_lds16(gB1, &b_tile[buf ^ 1][sA1]);
            gld_lds16(gB2, &b_tile[buf ^ 1][sA2]);
        }

        short8 bf[6];
        #pragma unroll
        for (int ni = 0; ni < 6; ++ni)
            bf[ni] = *(const short8*)&b_tile[buf][(wn * 96 + ni * 16 + lc) * 32 + quad * 8];
        #pragma unroll
        for (int mi = 0; mi < 4; ++mi) {
            short8 af = *(const short8*)&a_tile[buf][(wm * 64 + mi * 16 + lc) * 32 + quad * 8];
            #pragma unroll
            for (int ni = 0; ni < 6; ++ni)
                acc[mi][ni] = __builtin_amdgcn_mfma_f32_16x16x32_bf16(af, bf[ni], acc[mi][ni], 0, 0, 0);
        }
        buf ^= 1;
    }

    #pragma unroll
    for (int mi = 0; mi < 4; ++mi) {
        const int rbase = row0 + wm * 64 + mi * 16 + quad * 4;
        #pragma unroll
        for (int ni = 0; ni < 6; ++ni) {
            const int colbase = col0 + wn * 96 + ni * 16;
            const int col = colbase + lc;
            if (colbase < 2 * DD) {
                const float sc = (colbase < DD) ? qscale : 1.0f;
                #pragma unroll
                for (int r = 0; r < 4; ++r)
                    Cout[(size_t)(rbase + r) * N + col] = f2b(acc[mi][ni][r] * sc);
            } else {
                const int vcol = col - 2 * DD;
                const int hh = vcol >> 6, d = vcol & 63;
                const int bq = rbase >> 11, tt = rbase & 2047;
                uint2v pk;
                pk.x = cvtpk(acc[mi][ni][0], acc[mi][ni][1]);
                pk.y = cvtpk(acc[mi][ni][2], acc[mi][ni][3]);
                *(uint2v*)&vt_out[(size_t)((bq * 16 + hh) * 64 + d) * TT + tt] = pk;
            }
        }
    }
}

// ---------------------------------------------------------------------------
// out-proj GEMM (128x128 block, 64x64 wave) : C fp32 = A * Bt^T.
// BK=64, XOR-swizzled LDS (pre-swizzled source col + ^(row&7) read offset,
// linear gld_lds dest). LDS 64 KB dbuf -> 2 blocks/CU.
// ---------------------------------------------------------------------------
__global__ __launch_bounds__(256, 2)
void gemm_out(const unsigned short* __restrict__ A,
              const unsigned short* __restrict__ Bt,
              float* __restrict__ Cout, int M, int N, int K) {
    __shared__ unsigned short a_tile[2][128 * 64];   // 16 KB/buf
    __shared__ unsigned short b_tile[2][128 * 64];   // 16 KB/buf
    const int tid  = threadIdx.x;
    const int wave = tid >> 6;
    const int lane = tid & 63;
    const int quad = lane >> 4;
    const int lc   = lane & 15;
    const int wm = wave >> 1, wn = wave & 1;
    const int row0 = blockIdx.y * 128;
    const int col0 = blockIdx.x * 128;

    const int srow = lane >> 3;
    const int scol = ((lane & 7) ^ srow) * 8;
    const unsigned short* gA0 = A  + (size_t)(row0 + (wave     ) * 8 + srow) * K + scol;
    const unsigned short* gA1 = A  + (size_t)(row0 + (wave +  4) * 8 + srow) * K + scol;
    const unsigned short* gA2 = A  + (size_t)(row0 + (wave +  8) * 8 + srow) * K + scol;
    const unsigned short* gA3 = A  + (size_t)(row0 + (wave + 12) * 8 + srow) * K + scol;
    const unsigned short* gB0 = Bt + (size_t)(col0 + (wave     ) * 8 + srow) * K + scol;
    const unsigned short* gB1 = Bt + (size_t)(col0 + (wave +  4) * 8 + srow) * K + scol;
    const unsigned short* gB2 = Bt + (size_t)(col0 + (wave +  8) * 8 + srow) * K + scol;
    const unsigned short* gB3 = Bt + (size_t)(col0 + (wave + 12) * 8 + srow) * K + scol;
    const int s0 = (wave     ) * 512, s1 = (wave +  4) * 512;
    const int s2 = (wave +  8) * 512, s3 = (wave + 12) * 512;

    int arow[4], brow[4];
    #pragma unroll
    for (int mi = 0; mi < 4; ++mi) arow[mi] = (wm * 64 + mi * 16 + lc) * 64;
    #pragma unroll
    for (int ni = 0; ni < 4; ++ni) brow[ni] = (wn * 64 + ni * 16 + lc) * 64;
    const int sx0 = ((quad    ) ^ (lc & 7)) * 8;
    const int sx1 = ((quad + 4) ^ (lc & 7)) * 8;

    floatx4 acc[4][4];
    #pragma unroll
    for (int i = 0; i < 4; i++)
        #pragma unroll
        for (int j = 0; j < 4; j++)
            acc[i][j] = (floatx4){0.f, 0.f, 0.f, 0.f};

    gld_lds16(gA0, &a_tile[0][s0]);
    gld_lds16(gA1, &a_tile[0][s1]);
    gld_lds16(gA2, &a_tile[0][s2]);
    gld_lds16(gA3, &a_tile[0][s3]);
    gld_lds16(gB0, &b_tile[0][s0]);
    gld_lds16(gB1, &b_tile[0][s1]);
    gld_lds16(gB2, &b_tile[0][s2]);
    gld_lds16(gB3, &b_tile[0][s3]);
    int buf = 0;

    const int nkt = K >> 6;   // 16
    for (int kt = 0; kt < nkt; ++kt) {
        __syncthreads();
        if (kt + 1 < nkt) {
            gA0 += 64; gA1 += 64; gA2 += 64; gA3 += 64;
            gB0 += 64; gB1 += 64; gB2 += 64; gB3 += 64;
            gld_lds16(gA0, &a_tile[buf ^ 1][s0]);
            gld_lds16(gA1, &a_tile[buf ^ 1][s1]);
            gld_lds16(gA2, &a_tile[buf ^ 1][s2]);
            gld_lds16(gA3, &a_tile[buf ^ 1][s3]);
            gld_lds16(gB0, &b_tile[buf ^ 1][s0]);
            gld_lds16(gB1, &b_tile[buf ^ 1][s1]);
            gld_lds16(gB2, &b_tile[buf ^ 1][s2]);
            gld_lds16(gB3, &b_tile[buf ^ 1][s3]);
        }

        short8 af[4], bf[4];
        #pragma unroll
        for (int mi = 0; mi < 4; ++mi)
            af[mi] = *(const short8*)&a_tile[buf][arow[mi] + sx0];
        #pragma unroll
        for (int ni = 0; ni < 4; ++ni)
            bf[ni] = *(const short8*)&b_tile[buf][brow[ni] + sx0];
        #pragma unroll
        for (int mi = 0; mi < 4; ++mi)
            #pragma unroll
            for (int ni = 0; ni < 4; ++ni)
                acc[mi][ni] = __builtin_amdgcn_mfma_f32_16x16x32_bf16(af[mi], bf[ni], acc[mi][ni], 0, 0, 0);
        #pragma unroll
        for (int mi = 0; mi < 4; ++mi)
            af[mi] = *(const short8*)&a_tile[buf][arow[mi] + sx1];
        #pragma unroll
        for (int ni = 0; ni < 4; ++ni)
            bf[ni] = *(const short8*)&b_tile[buf][brow[ni] + sx1];
        #pragma unroll
        for (int mi = 0; mi < 4; ++mi)
            #pragma unroll
            for (int ni = 0; ni < 4; ++ni)
                acc[mi][ni] = __builtin_amdgcn_mfma_f32_16x16x32_bf16(af[mi], bf[ni], acc[mi][ni], 0, 0, 0);
        buf ^= 1;
    }

    #pragma unroll
    for (int mi = 0; mi < 4; ++mi) {
        const int rbase = row0 + wm * 64 + mi * 16 + quad * 4;
        #pragma unroll
        for (int ni = 0; ni < 4; ++ni) {
            const int col = col0 + wn * 64 + ni * 16 + lc;
            #pragma unroll
            for (int r = 0; r < 4; ++r)
                Cout[(size_t)(rbase + r) * N + col] = acc[mi][ni][r];
        }
    }
}

// ---------------------------------------------------------------------------
// Flash attention (R7 version). Causal, no-max softmax. Unpaired q-tiles:
// grid (B*H, 16), block handles one q-tile j = 15 - blockIdx.y (long blocks
// dispatch first). 1024 blocks + 50 KB LDS -> 3 blocks/CU. Same-bh blocks
// land on the same XCD (stride 64 % 8 == 0) -> K/V L2-local. Per-step:
// vf hoist, split softmax halves writing DISJOINT p_lds rows, pf split
// reads, setprio on MFMA clusters, cvt_pk packing.
// ---------------------------------------------------------------------------
__global__ __launch_bounds__(256, 3)
void attn_fwd(const unsigned short* __restrict__ qkv,
              const unsigned short* __restrict__ vt,
              unsigned short* __restrict__ out) {
    __shared__ unsigned short kbuf[2][64 * 64];
    __shared__ unsigned short vbuf[2][64 * 64];
    __shared__ unsigned short p_lds[4][32 * 72];
    const int bh = blockIdx.x;
    const int b = bh >> 4, h = bh & 15;
    const int j = 15 - blockIdx.y;        // q-tile index, long tiles first
    const int tid = threadIdx.x;
    const int wave = tid >> 6, lane = tid & 63;
    const int quad = lane >> 4, lc = lane & 15;
    unsigned short* pw = p_lds[wave];

    const int sr = wave * 8 + (lane >> 3);
    const int lg = (lane & 7) ^ (sr & 7);
    const unsigned short* ksrc0 = qkv + (size_t)(b * TT + sr) * N1 + DD + h * HDIM + lg * 8;
    const unsigned short* vsrc0 = vt + (size_t)(bh * HDIM + sr) * TT + lg * 8;
    const int stg = wave * 512;

    int fofs[4][2];
    #pragma unroll
    for (int mi = 0; mi < 4; ++mi)
        #pragma unroll
        for (int kk = 0; kk < 2; ++kk)
            fofs[mi][kk] = (mi * 16 + lc) * 64 + (((kk * 4 + quad) ^ (lc & 7)) * 8);

    gld_lds16(ksrc0, &kbuf[0][stg]);
    gld_lds16(ksrc0 + 32 * (size_t)N1, &kbuf[0][stg + 2048]);
    gld_lds16(vsrc0, &vbuf[0][stg]);
    gld_lds16(vsrc0 + 32 * (size_t)TT, &vbuf[0][stg + 2048]);
    int buf = 0;

    const int q0 = j * 128;
    const int r0 = q0 + wave * 32;
    const int tmax = 2 * j + 1;

    short8 qf[2][2];
    #pragma unroll
    for (int ni = 0; ni < 2; ++ni)
        #pragma unroll
        for (int kk = 0; kk < 2; ++kk)
            qf[ni][kk] = *(const short8*)(qkv + (size_t)(b * TT + r0 + ni * 16 + lc) * N1 + h * HDIM + kk * 32 + quad * 8);

    float lp[2] = {0.f, 0.f};
    floatx4 o_acc[4][2];
    #pragma unroll
    for (int mi = 0; mi < 4; ++mi)
        #pragma unroll
        for (int ni = 0; ni < 2; ++ni)
            o_acc[mi][ni] = (floatx4){0.f, 0.f, 0.f, 0.f};

    for (int t = 0; t <= tmax; ++t) {
        const int kv0 = t * 64;
        __syncthreads();

        if (t < tmax) {
            const unsigned short* ks = ksrc0 + (size_t)(t + 1) * 64 * N1;
            const unsigned short* vs = vsrc0 + (t + 1) * 64;
            gld_lds16(ks, &kbuf[buf ^ 1][stg]);
            gld_lds16(ks + 32 * (size_t)N1, &kbuf[buf ^ 1][stg + 2048]);
            gld_lds16(vs, &vbuf[buf ^ 1][stg]);
            gld_lds16(vs + 32 * (size_t)TT, &vbuf[buf ^ 1][stg + 2048]);
        }

        // K and V fragment reads together: 16 independent b128 reads
        // stream through the LDS pipe while QK^T MFMAs run.
        short8 kf[4][2], vf[4][2];
        #pragma unroll
        for (int mi = 0; mi < 4; ++mi)
            #pragma unroll
            for (int kk = 0; kk < 2; ++kk)
                kf[mi][kk] = *(const short8*)&kbuf[buf][fofs[mi][kk]];
        #pragma unroll
        for (int mi = 0; mi < 4; ++mi)
            #pragma unroll
            for (int kk = 0; kk < 2; ++kk)
                vf[mi][kk] = *(const short8*)&vbuf[buf][fofs[mi][kk]];

        floatx4 sa[4][2];
        __builtin_amdgcn_s_setprio(1);
        #pragma unroll
        for (int mi = 0; mi < 4; ++mi)
            #pragma unroll
            for (int ni = 0; ni < 2; ++ni) {
                floatx4 z = (floatx4){0.f, 0.f, 0.f, 0.f};
                z = __builtin_amdgcn_mfma_f32_16x16x32_bf16(kf[mi][0], qf[ni][0], z, 0, 0, 0);
                z = __builtin_amdgcn_mfma_f32_16x16x32_bf16(kf[mi][1], qf[ni][1], z, 0, 0, 0);
                sa[mi][ni] = z;
            }
        __builtin_amdgcn_s_setprio(0);

        if (kv0 + 63 > r0) {
            #pragma unroll
            for (int ni = 0; ni < 2; ++ni) {
                const int qg = r0 + ni * 16 + lc;
                #pragma unroll
                for (int mi = 0; mi < 4; ++mi) {
                    const int kvb = kv0 + mi * 16 + quad * 4;
                    #pragma unroll
                    for (int r = 0; r < 4; ++r)
                        sa[mi][ni][r] = (kvb + r <= qg) ? sa[mi][ni][r] : -1e30f;
                }
            }
        }

        short8 pf[2][2];

        // softmax half ni=0: exp + pack + write rows 0..15
        {
            float rs = 0.f;
            #pragma unroll
            for (int mi = 0; mi < 4; ++mi) {
                float p0 = __builtin_amdgcn_exp2f(sa[mi][0][0]);
                float p1 = __builtin_amdgcn_exp2f(sa[mi][0][1]);
                float p2 = __builtin_amdgcn_exp2f(sa[mi][0][2]);
                float p3 = __builtin_amdgcn_exp2f(sa[mi][0][3]);
                rs += (p0 + p1) + (p2 + p3);
                uint2v pk;
                pk.x = cvtpk(p0, p1);
                pk.y = cvtpk(p2, p3);
                *(uint2v*)&pw[lc * 72 + mi * 16 + quad * 4] = pk;
            }
            lp[0] += rs;
        }
        // pf[0] reads: write->read latency hides under ni=1's exp/cvtpk
        #pragma unroll
        for (int kk = 0; kk < 2; ++kk)
            pf[0][kk] = *(const short8*)&pw[lc * 72 + kk * 32 + quad * 8];

        // softmax half ni=1: exp + pack + write rows 16..31
        {
            float rs = 0.f;
            #pragma unroll
            for (int mi = 0; mi < 4; ++mi) {
                float p0 = __builtin_amdgcn_exp2f(sa[mi][1][0]);
                float p1 = __builtin_amdgcn_exp2f(sa[mi][1][1]);
                float p2 = __builtin_amdgcn_exp2f(sa[mi][1][2]);
                float p3 = __builtin_amdgcn_exp2f(sa[mi][1][3]);
                rs += (p0 + p1) + (p2 + p3);
                uint2v pk;
                pk.x = cvtpk(p0, p1);
                pk.y = cvtpk(p2, p3);
                *(uint2v*)&pw[(16 + lc) * 72 + mi * 16 + quad * 4] = pk;
            }
            lp[1] += rs;
        }
        #pragma unroll
        for (int kk = 0; kk < 2; ++kk)
            pf[1][kk] = *(const short8*)&pw[(16 + lc) * 72 + kk * 32 + quad * 8];

        __builtin_amdgcn_s_setprio(1);
        #pragma unroll
        for (int mi = 0; mi < 4; ++mi)
            #pragma unroll
            for (int ni = 0; ni < 2; ++ni) {
                o_acc[mi][ni] = __builtin_amdgcn_mfma_f32_16x16x32_bf16(vf[mi][0], pf[ni][0], o_acc[mi][ni], 0, 0, 0);
                o_acc[mi][ni] = __builtin_amdgcn_mfma_f32_16x16x32_bf16(vf[mi][1], pf[ni][1], o_acc[mi][ni], 0, 0, 0);
            }
        __builtin_amdgcn_s_setprio(0);

        buf ^= 1;
    }

    #pragma unroll
    for (int ni = 0; ni < 2; ++ni) {
        float lt = lp[ni];
        lt += __shfl_xor(lt, 16);
        lt += __shfl_xor(lt, 32);
        const float inv = 1.0f / lt;
        const size_t tok = (size_t)(b * TT + r0 + ni * 16 + lc);
        #pragma unroll
        for (int mi = 0; mi < 4; ++mi) {
            uint2v pk;
            pk.x = cvtpk(o_acc[mi][ni][0] * inv, o_acc[mi][ni][1] * inv);
            pk.y = cvtpk(o_acc[mi][ni][2] * inv, o_acc[mi][ni][3] * inv);
            *(uint2v*)&out[tok * DD + h * HDIM + mi * 16 + quad * 4] = pk;
        }
    }
}

// ---------------------------------------------------------------------------
extern "C" void kernel_launch(void* const* d_in, const int* in_sizes, int n_in,
                              void* d_out, int out_size, void* d_ws, size_t ws_size,
                              hipStream_t stream) {
    const float* x     = (const float*)d_in[0];   // [B,T,D]
    const float* w_qkv = (const float*)d_in[1];   // [D, 3D]
    const float* w_out = (const float*)d_in[2];   // [D, D]
    float* out = (float*)d_out;                   // [B,T,D] fp32

    unsigned short* ws  = (unsigned short*)d_ws;
    unsigned short* xb  = ws;                                  // 8192*1024 (reused for attn out)
    unsigned short* qkv = xb  + (size_t)BT * DD;               // 8192*3072 (V third unused)
    unsigned short* wqT = qkv + (size_t)BT * N1;               // 3072*1024
    unsigned short* woT = wqT + (size_t)N1 * DD;               // 1024*1024
    unsigned short* vtb = woT + (size_t)DD * DD;               // 4096*2048

    const float QSCALE = 0.18033688011112042f;  // (1/8) * log2(e)

    // 1. fused prep: x->bf16, w_qkv->wqT, w_out->woT (one launch)
    prep<<<6144, 256, 0, stream>>>(x, xb, w_qkv, wqT, w_out, woT);
    // 2. QKV = x @ w_qkv (Q pre-scaled; V written transposed to vtb)
    gemm_qkv<<<dim3(N1 / 192, BT / 128), 256, 0, stream>>>(xb, wqT, qkv, BT, N1, DD, QSCALE, vtb);
    // 3. flash attention (writes over xb); one q-tile per block, long first
    attn_fwd<<<dim3(BB * HH, 16), 256, 0, stream>>>(qkv, vtb, xb);
    // 4. out = attn @ w_out (fp32 out)
    gemm_out<<<dim3(DD / 128, BT / 128), 256, 0, stream>>>(xb, woT, out, BT, DD, DD);
}

// Round 13
// 220.576 us; speedup vs baseline: 1.0682x; 1.0682x over previous
//
#include <hip/hip_runtime.h>
#include <stdint.h>
#include <stddef.h>

#define BB 4
#define TT 2048
#define DD 1024
#define HH 16
#define HDIM 64
#define BT (BB*TT)      // 8192 tokens
#define N1 (3*DD)       // 3072

typedef __attribute__((ext_vector_type(8))) short short8;
typedef __attribute__((ext_vector_type(4))) float floatx4;
typedef __attribute__((ext_vector_type(4))) unsigned short ushortx4;
typedef __attribute__((ext_vector_type(2))) unsigned int uint2v;

// fp32 -> bf16, round-to-nearest-even (scalar path)
__device__ __forceinline__ unsigned short f2b(float f) {
    unsigned int u = __float_as_uint(f);
    u += 0x7fffu + ((u >> 16) & 1u);
    return (unsigned short)(u >> 16);
}

// HW packed fp32x2 -> bf16x2 (gfx950 v_cvt_pk_bf16_f32, RNE). low16=a, high16=b.
__device__ __forceinline__ unsigned int cvtpk(float a, float b) {
    unsigned int r;
    asm("v_cvt_pk_bf16_f32 %0, %1, %2" : "=v"(r) : "v"(a), "v"(b));
    return r;
}

// async global->LDS, 16B per lane; dest is wave-uniform base + lane*16
__device__ __forceinline__ void gld_lds16(const void* g, void* l) {
    __builtin_amdgcn_global_load_lds(
        (__attribute__((address_space(1))) void*)(g),
        (__attribute__((address_space(3))) void*)(l), 16, 0, 0);
}

// ---------------------------------------------------------------------------
// Fused prep: one launch replaces {cvt_bf16, transpose_cvt x2}.
//   blocks [0, 2048)        : x fp32 -> bf16, 16 floats/thread
//   blocks [2048, 5120)     : w_qkv [1024][3072] -> wqT [3072][1024] bf16
//   blocks [5120, 6144)     : w_out [1024][1024] -> woT [1024][1024] bf16
// ---------------------------------------------------------------------------
__global__ __launch_bounds__(256)
void prep(const float* __restrict__ x, unsigned short* __restrict__ xb,
          const float* __restrict__ w_qkv, unsigned short* __restrict__ wqT,
          const float* __restrict__ w_out, unsigned short* __restrict__ woT) {
    __shared__ float tile[32][33];
    const int bid = blockIdx.x;
    const int tid = threadIdx.x;
    if (bid < 2048) {
        const floatx4* src = (const floatx4*)x;
        ushortx4* dst = (ushortx4*)xb;
        const int base = bid * 1024 + tid;   // float4 units
        #pragma unroll
        for (int it = 0; it < 4; ++it) {
            const int i = base + it * 256;
            floatx4 f = src[i];
            ushortx4 o;
            o.x = f2b(f.x); o.y = f2b(f.y); o.z = f2b(f.z); o.w = f2b(f.w);
            dst[i] = o;
        }
        return;
    }
    const float* src;
    unsigned short* dst;
    int R, C, cx, ry;
    if (bid < 5120) {
        const int t = bid - 2048;
        cx = t % 96; ry = t / 96; src = w_qkv; dst = wqT; R = DD; C = N1;
    } else {
        const int t = bid - 5120;
        cx = t & 31; ry = t >> 5; src = w_out; dst = woT; R = DD; C = DD;
    }
    const int c0 = cx * 32, r0 = ry * 32;
    const int xx = tid & 31, y0 = tid >> 5;
    for (int yy = y0; yy < 32; yy += 8)
        tile[yy][xx] = src[(size_t)(r0 + yy) * C + c0 + xx];
    __syncthreads();
    for (int yy = y0; yy < 32; yy += 8)
        dst[(size_t)(c0 + yy) * R + r0 + xx] = f2b(tile[xx][yy]);
}

// ---------------------------------------------------------------------------
// QKV GEMM (R11 version, reverted from R12's failed 128-row tile):
// C[M,3072] = A[M,1024]*Bt^T. Block tile 256x192, 4 waves, wave tile
// 128x96 (acc[8][6]). Grid (16,32)=512 blocks; dbuf LDS 56 KB -> exactly
// 2 blocks/CU. Tile-space closed: 128-row (R12, 97us), mono-512-thread
// (R2/R3, 75-81us) both lose to this 65us structure.
// XCD swizzle: swz=(lin&7)*64+(lin>>3); each XCD serves 4 complete
// row-panels (halves FETCH 68.8->33 MB, measured R11).
// Epilogue: cols [0,1024) bf16*qscale, [1024,2048) bf16, [2048,3072)
// written transposed to vt as [bh*64+d][T] bf16 (packed via v_cvt_pk).
// ---------------------------------------------------------------------------
__global__ __launch_bounds__(256, 2)
void gemm_qkv(const unsigned short* __restrict__ A,
              const unsigned short* __restrict__ Bt,
              unsigned short* __restrict__ Cout, int M, int N, int K,
              float qscale, unsigned short* __restrict__ vt_out) {
    __shared__ unsigned short a_tile[2][256 * 32];
    __shared__ unsigned short b_tile[2][192 * 32];
    const int tid  = threadIdx.x;
    const int wave = tid >> 6;
    const int lane = tid & 63;
    const int quad = lane >> 4;
    const int lc   = lane & 15;
    const int wm = wave >> 1, wn = wave & 1;   // wave tile: rows wm*128, cols wn*96
    // XCD-aware remap: XCD k (lin%8==k) handles row-panels [4k, 4k+4)
    const int lin = blockIdx.y * 16 + blockIdx.x;
    const int swz = (lin & 7) * 64 + (lin >> 3);
    const int row0 = (swz >> 4) * 256;
    const int col0 = (swz & 15) * 192;

    const int r_in = lane >> 2;
    const int kseg = (lane & 3) * 8;
    const unsigned short* gA0 = A  + (size_t)(row0 + (wave     ) * 16 + r_in) * K + kseg;
    const unsigned short* gA1 = A  + (size_t)(row0 + (wave +  4) * 16 + r_in) * K + kseg;
    const unsigned short* gA2 = A  + (size_t)(row0 + (wave +  8) * 16 + r_in) * K + kseg;
    const unsigned short* gA3 = A  + (size_t)(row0 + (wave + 12) * 16 + r_in) * K + kseg;
    const unsigned short* gB0 = Bt + (size_t)(col0 + (wave     ) * 16 + r_in) * K + kseg;
    const unsigned short* gB1 = Bt + (size_t)(col0 + (wave +  4) * 16 + r_in) * K + kseg;
    const unsigned short* gB2 = Bt + (size_t)(col0 + (wave +  8) * 16 + r_in) * K + kseg;
    const int sA0 = (wave     ) * 512, sA1 = (wave +  4) * 512;
    const int sA2 = (wave +  8) * 512, sA3 = (wave + 12) * 512;

    floatx4 acc[8][6];
    #pragma unroll
    for (int i = 0; i < 8; i++)
        #pragma unroll
        for (int j = 0; j < 6; j++)
            acc[i][j] = (floatx4){0.f, 0.f, 0.f, 0.f};

    gld_lds16(gA0, &a_tile[0][sA0]);
    gld_lds16(gA1, &a_tile[0][sA1]);
    gld_lds16(gA2, &a_tile[0][sA2]);
    gld_lds16(gA3, &a_tile[0][sA3]);
    gld_lds16(gB0, &b_tile[0][sA0]);
    gld_lds16(gB1, &b_tile[0][sA1]);
    gld_lds16(gB2, &b_tile[0][sA2]);
    int buf = 0;

    const int nkt = K >> 5;
    for (int kt = 0; kt < nkt; ++kt) {
        __syncthreads();
        if (kt + 1 < nkt) {
            gA0 += 32; gA1 += 32; gA2 += 32; gA3 += 32;
            gB0 += 32; gB1 += 32; gB2 += 32;
            gld_lds16(gA0, &a_tile[buf ^ 1][sA0]);
            gld_lds16(gA1, &a_tile[buf ^ 1][sA1]);
            gld_lds16(gA2, &a_tile[buf ^ 1][sA2]);
            gld_lds16(gA3, &a_tile[buf ^ 1][sA3]);
            gld_lds16(gB0, &b_tile[buf ^ 1][sA0]);
            gld_lds16(gB1, &b_tile[buf ^ 1][sA1]);
            gld_lds16(gB2, &b_tile[buf ^ 1][sA2]);
        }

        short8 bf[6];
        #pragma unroll
        for (int ni = 0; ni < 6; ++ni)
            bf[ni] = *(const short8*)&b_tile[buf][(wn * 96 + ni * 16 + lc) * 32 + quad * 8];
        #pragma unroll
        for (int mi = 0; mi < 8; ++mi) {
            short8 af = *(const short8*)&a_tile[buf][(wm * 128 + mi * 16 + lc) * 32 + quad * 8];
            #pragma unroll
            for (int ni = 0; ni < 6; ++ni)
                acc[mi][ni] = __builtin_amdgcn_mfma_f32_16x16x32_bf16(af, bf[ni], acc[mi][ni], 0, 0, 0);
        }
        buf ^= 1;
    }

    #pragma unroll
    for (int mi = 0; mi < 8; ++mi) {
        const int rbase = row0 + wm * 128 + mi * 16 + quad * 4;
        #pragma unroll
        for (int ni = 0; ni < 6; ++ni) {
            const int colbase = col0 + wn * 96 + ni * 16;
            const int col = colbase + lc;
            if (colbase < 2 * DD) {
                const float sc = (colbase < DD) ? qscale : 1.0f;
                #pragma unroll
                for (int r = 0; r < 4; ++r)
                    Cout[(size_t)(rbase + r) * N + col] = f2b(acc[mi][ni][r] * sc);
            } else {
                const int vcol = col - 2 * DD;
                const int hh = vcol >> 6, d = vcol & 63;
                const int bq = rbase >> 11, tt = rbase & 2047;
                uint2v pk;
                pk.x = cvtpk(acc[mi][ni][0], acc[mi][ni][1]);
                pk.y = cvtpk(acc[mi][ni][2], acc[mi][ni][3]);
                *(uint2v*)&vt_out[(size_t)((bq * 16 + hh) * 64 + d) * TT + tt] = pk;
            }
        }
    }
}

// ---------------------------------------------------------------------------
// out-proj GEMM (128x128 block, 64x64 wave) : C fp32 = A * Bt^T.
// BK=64, XOR-swizzled LDS (pre-swizzled source col + ^(row&7) read offset,
// linear gld_lds dest). LDS 64 KB dbuf -> 2 blocks/CU.
// R13: XCD-aware block swizzle (same proven pattern as gemm_qkv): 512
// blocks, swz=(lin&7)*64+(lin>>3), each XCD serves 8 complete row-panels
// (2 MB A, L2-resident).
// ---------------------------------------------------------------------------
__global__ __launch_bounds__(256, 2)
void gemm_out(const unsigned short* __restrict__ A,
              const unsigned short* __restrict__ Bt,
              float* __restrict__ Cout, int M, int N, int K) {
    __shared__ unsigned short a_tile[2][128 * 64];   // 16 KB/buf
    __shared__ unsigned short b_tile[2][128 * 64];   // 16 KB/buf
    const int tid  = threadIdx.x;
    const int wave = tid >> 6;
    const int lane = tid & 63;
    const int quad = lane >> 4;
    const int lc   = lane & 15;
    const int wm = wave >> 1, wn = wave & 1;
    // XCD-aware remap (512 blocks, 8 col-tiles x 64 row-tiles)
    const int lin = blockIdx.y * 8 + blockIdx.x;
    const int swz = (lin & 7) * 64 + (lin >> 3);
    const int row0 = (swz >> 3) * 128;
    const int col0 = (swz & 7) * 128;

    const int srow = lane >> 3;
    const int scol = ((lane & 7) ^ srow) * 8;
    const unsigned short* gA0 = A  + (size_t)(row0 + (wave     ) * 8 + srow) * K + scol;
    const unsigned short* gA1 = A  + (size_t)(row0 + (wave +  4) * 8 + srow) * K + scol;
    const unsigned short* gA2 = A  + (size_t)(row0 + (wave +  8) * 8 + srow) * K + scol;
    const unsigned short* gA3 = A  + (size_t)(row0 + (wave + 12) * 8 + srow) * K + scol;
    const unsigned short* gB0 = Bt + (size_t)(col0 + (wave     ) * 8 + srow) * K + scol;
    const unsigned short* gB1 = Bt + (size_t)(col0 + (wave +  4) * 8 + srow) * K + scol;
    const unsigned short* gB2 = Bt + (size_t)(col0 + (wave +  8) * 8 + srow) * K + scol;
    const unsigned short* gB3 = Bt + (size_t)(col0 + (wave + 12) * 8 + srow) * K + scol;
    const int s0 = (wave     ) * 512, s1 = (wave +  4) * 512;
    const int s2 = (wave +  8) * 512, s3 = (wave + 12) * 512;

    int arow[4], brow[4];
    #pragma unroll
    for (int mi = 0; mi < 4; ++mi) arow[mi] = (wm * 64 + mi * 16 + lc) * 64;
    #pragma unroll
    for (int ni = 0; ni < 4; ++ni) brow[ni] = (wn * 64 + ni * 16 + lc) * 64;
    const int sx0 = ((quad    ) ^ (lc & 7)) * 8;
    const int sx1 = ((quad + 4) ^ (lc & 7)) * 8;

    floatx4 acc[4][4];
    #pragma unroll
    for (int i = 0; i < 4; i++)
        #pragma unroll
        for (int j = 0; j < 4; j++)
            acc[i][j] = (floatx4){0.f, 0.f, 0.f, 0.f};

    gld_lds16(gA0, &a_tile[0][s0]);
    gld_lds16(gA1, &a_tile[0][s1]);
    gld_lds16(gA2, &a_tile[0][s2]);
    gld_lds16(gA3, &a_tile[0][s3]);
    gld_lds16(gB0, &b_tile[0][s0]);
    gld_lds16(gB1, &b_tile[0][s1]);
    gld_lds16(gB2, &b_tile[0][s2]);
    gld_lds16(gB3, &b_tile[0][s3]);
    int buf = 0;

    const int nkt = K >> 6;   // 16
    for (int kt = 0; kt < nkt; ++kt) {
        __syncthreads();
        if (kt + 1 < nkt) {
            gA0 += 64; gA1 += 64; gA2 += 64; gA3 += 64;
            gB0 += 64; gB1 += 64; gB2 += 64; gB3 += 64;
            gld_lds16(gA0, &a_tile[buf ^ 1][s0]);
            gld_lds16(gA1, &a_tile[buf ^ 1][s1]);
            gld_lds16(gA2, &a_tile[buf ^ 1][s2]);
            gld_lds16(gA3, &a_tile[buf ^ 1][s3]);
            gld_lds16(gB0, &b_tile[buf ^ 1][s0]);
            gld_lds16(gB1, &b_tile[buf ^ 1][s1]);
            gld_lds16(gB2, &b_tile[buf ^ 1][s2]);
            gld_lds16(gB3, &b_tile[buf ^ 1][s3]);
        }

        short8 af[4], bf[4];
        #pragma unroll
        for (int mi = 0; mi < 4; ++mi)
            af[mi] = *(const short8*)&a_tile[buf][arow[mi] + sx0];
        #pragma unroll
        for (int ni = 0; ni < 4; ++ni)
            bf[ni] = *(const short8*)&b_tile[buf][brow[ni] + sx0];
        #pragma unroll
        for (int mi = 0; mi < 4; ++mi)
            #pragma unroll
            for (int ni = 0; ni < 4; ++ni)
                acc[mi][ni] = __builtin_amdgcn_mfma_f32_16x16x32_bf16(af[mi], bf[ni], acc[mi][ni], 0, 0, 0);
        #pragma unroll
        for (int mi = 0; mi < 4; ++mi)
            af[mi] = *(const short8*)&a_tile[buf][arow[mi] + sx1];
        #pragma unroll
        for (int ni = 0; ni < 4; ++ni)
            bf[ni] = *(const short8*)&b_tile[buf][brow[ni] + sx1];
        #pragma unroll
        for (int mi = 0; mi < 4; ++mi)
            #pragma unroll
            for (int ni = 0; ni < 4; ++ni)
                acc[mi][ni] = __builtin_amdgcn_mfma_f32_16x16x32_bf16(af[mi], bf[ni], acc[mi][ni], 0, 0, 0);
        buf ^= 1;
    }

    #pragma unroll
    for (int mi = 0; mi < 4; ++mi) {
        const int rbase = row0 + wm * 64 + mi * 16 + quad * 4;
        #pragma unroll
        for (int ni = 0; ni < 4; ++ni) {
            const int col = col0 + wn * 64 + ni * 16 + lc;
            #pragma unroll
            for (int r = 0; r < 4; ++r)
                Cout[(size_t)(rbase + r) * N + col] = acc[mi][ni][r];
        }
    }
}

// ---------------------------------------------------------------------------
// Flash attention (R7 version). Causal, no-max softmax. Unpaired q-tiles:
// grid (B*H, 16), block handles one q-tile j = 15 - blockIdx.y (long blocks
// dispatch first). 1024 blocks + 50 KB LDS -> 3 blocks/CU. Same-bh blocks
// land on the same XCD (stride 64 % 8 == 0) -> K/V L2-local. Per-step:
// vf hoist, split softmax halves writing DISJOINT p_lds rows, pf split
// reads, setprio on MFMA clusters, cvt_pk packing.
// ---------------------------------------------------------------------------
__global__ __launch_bounds__(256, 3)
void attn_fwd(const unsigned short* __restrict__ qkv,
              const unsigned short* __restrict__ vt,
              unsigned short* __restrict__ out) {
    __shared__ unsigned short kbuf[2][64 * 64];
    __shared__ unsigned short vbuf[2][64 * 64];
    __shared__ unsigned short p_lds[4][32 * 72];
    const int bh = blockIdx.x;
    const int b = bh >> 4, h = bh & 15;
    const int j = 15 - blockIdx.y;        // q-tile index, long tiles first
    const int tid = threadIdx.x;
    const int wave = tid >> 6, lane = tid & 63;
    const int quad = lane >> 4, lc = lane & 15;
    unsigned short* pw = p_lds[wave];

    const int sr = wave * 8 + (lane >> 3);
    const int lg = (lane & 7) ^ (sr & 7);
    const unsigned short* ksrc0 = qkv + (size_t)(b * TT + sr) * N1 + DD + h * HDIM + lg * 8;
    const unsigned short* vsrc0 = vt + (size_t)(bh * HDIM + sr) * TT + lg * 8;
    const int stg = wave * 512;

    int fofs[4][2];
    #pragma unroll
    for (int mi = 0; mi < 4; ++mi)
        #pragma unroll
        for (int kk = 0; kk < 2; ++kk)
            fofs[mi][kk] = (mi * 16 + lc) * 64 + (((kk * 4 + quad) ^ (lc & 7)) * 8);

    gld_lds16(ksrc0, &kbuf[0][stg]);
    gld_lds16(ksrc0 + 32 * (size_t)N1, &kbuf[0][stg + 2048]);
    gld_lds16(vsrc0, &vbuf[0][stg]);
    gld_lds16(vsrc0 + 32 * (size_t)TT, &vbuf[0][stg + 2048]);
    int buf = 0;

    const int q0 = j * 128;
    const int r0 = q0 + wave * 32;
    const int tmax = 2 * j + 1;

    short8 qf[2][2];
    #pragma unroll
    for (int ni = 0; ni < 2; ++ni)
        #pragma unroll
        for (int kk = 0; kk < 2; ++kk)
            qf[ni][kk] = *(const short8*)(qkv + (size_t)(b * TT + r0 + ni * 16 + lc) * N1 + h * HDIM + kk * 32 + quad * 8);

    float lp[2] = {0.f, 0.f};
    floatx4 o_acc[4][2];
    #pragma unroll
    for (int mi = 0; mi < 4; ++mi)
        #pragma unroll
        for (int ni = 0; ni < 2; ++ni)
            o_acc[mi][ni] = (floatx4){0.f, 0.f, 0.f, 0.f};

    for (int t = 0; t <= tmax; ++t) {
        const int kv0 = t * 64;
        __syncthreads();

        if (t < tmax) {
            const unsigned short* ks = ksrc0 + (size_t)(t + 1) * 64 * N1;
            const unsigned short* vs = vsrc0 + (t + 1) * 64;
            gld_lds16(ks, &kbuf[buf ^ 1][stg]);
            gld_lds16(ks + 32 * (size_t)N1, &kbuf[buf ^ 1][stg + 2048]);
            gld_lds16(vs, &vbuf[buf ^ 1][stg]);
            gld_lds16(vs + 32 * (size_t)TT, &vbuf[buf ^ 1][stg + 2048]);
        }

        // K and V fragment reads together: 16 independent b128 reads
        // stream through the LDS pipe while QK^T MFMAs run.
        short8 kf[4][2], vf[4][2];
        #pragma unroll
        for (int mi = 0; mi < 4; ++mi)
            #pragma unroll
            for (int kk = 0; kk < 2; ++kk)
                kf[mi][kk] = *(const short8*)&kbuf[buf][fofs[mi][kk]];
        #pragma unroll
        for (int mi = 0; mi < 4; ++mi)
            #pragma unroll
            for (int kk = 0; kk < 2; ++kk)
                vf[mi][kk] = *(const short8*)&vbuf[buf][fofs[mi][kk]];

        floatx4 sa[4][2];
        __builtin_amdgcn_s_setprio(1);
        #pragma unroll
        for (int mi = 0; mi < 4; ++mi)
            #pragma unroll
            for (int ni = 0; ni < 2; ++ni) {
                floatx4 z = (floatx4){0.f, 0.f, 0.f, 0.f};
                z = __builtin_amdgcn_mfma_f32_16x16x32_bf16(kf[mi][0], qf[ni][0], z, 0, 0, 0);
                z = __builtin_amdgcn_mfma_f32_16x16x32_bf16(kf[mi][1], qf[ni][1], z, 0, 0, 0);
                sa[mi][ni] = z;
            }
        __builtin_amdgcn_s_setprio(0);

        if (kv0 + 63 > r0) {
            #pragma unroll
            for (int ni = 0; ni < 2; ++ni) {
                const int qg = r0 + ni * 16 + lc;
                #pragma unroll
                for (int mi = 0; mi < 4; ++mi) {
                    const int kvb = kv0 + mi * 16 + quad * 4;
                    #pragma unroll
                    for (int r = 0; r < 4; ++r)
                        sa[mi][ni][r] = (kvb + r <= qg) ? sa[mi][ni][r] : -1e30f;
                }
            }
        }

        short8 pf[2][2];

        // softmax half ni=0: exp + pack + write rows 0..15
        {
            float rs = 0.f;
            #pragma unroll
            for (int mi = 0; mi < 4; ++mi) {
                float p0 = __builtin_amdgcn_exp2f(sa[mi][0][0]);
                float p1 = __builtin_amdgcn_exp2f(sa[mi][0][1]);
                float p2 = __builtin_amdgcn_exp2f(sa[mi][0][2]);
                float p3 = __builtin_amdgcn_exp2f(sa[mi][0][3]);
                rs += (p0 + p1) + (p2 + p3);
                uint2v pk;
                pk.x = cvtpk(p0, p1);
                pk.y = cvtpk(p2, p3);
                *(uint2v*)&pw[lc * 72 + mi * 16 + quad * 4] = pk;
            }
            lp[0] += rs;
        }
        // pf[0] reads: write->read latency hides under ni=1's exp/cvtpk
        #pragma unroll
        for (int kk = 0; kk < 2; ++kk)
            pf[0][kk] = *(const short8*)&pw[lc * 72 + kk * 32 + quad * 8];

        // softmax half ni=1: exp + pack + write rows 16..31
        {
            float rs = 0.f;
            #pragma unroll
            for (int mi = 0; mi < 4; ++mi) {
                float p0 = __builtin_amdgcn_exp2f(sa[mi][1][0]);
                float p1 = __builtin_amdgcn_exp2f(sa[mi][1][1]);
                float p2 = __builtin_amdgcn_exp2f(sa[mi][1][2]);
                float p3 = __builtin_amdgcn_exp2f(sa[mi][1][3]);
                rs += (p0 + p1) + (p2 + p3);
                uint2v pk;
                pk.x = cvtpk(p0, p1);
                pk.y = cvtpk(p2, p3);
                *(uint2v*)&pw[(16 + lc) * 72 + mi * 16 + quad * 4] = pk;
            }
            lp[1] += rs;
        }
        #pragma unroll
        for (int kk = 0; kk < 2; ++kk)
            pf[1][kk] = *(const short8*)&pw[(16 + lc) * 72 + kk * 32 + quad * 8];

        __builtin_amdgcn_s_setprio(1);
        #pragma unroll
        for (int mi = 0; mi < 4; ++mi)
            #pragma unroll
            for (int ni = 0; ni < 2; ++ni) {
                o_acc[mi][ni] = __builtin_amdgcn_mfma_f32_16x16x32_bf16(vf[mi][0], pf[ni][0], o_acc[mi][ni], 0, 0, 0);
                o_acc[mi][ni] = __builtin_amdgcn_mfma_f32_16x16x32_bf16(vf[mi][1], pf[ni][1], o_acc[mi][ni], 0, 0, 0);
            }
        __builtin_amdgcn_s_setprio(0);

        buf ^= 1;
    }

    #pragma unroll
    for (int ni = 0; ni < 2; ++ni) {
        float lt = lp[ni];
        lt += __shfl_xor(lt, 16);
        lt += __shfl_xor(lt, 32);
        const float inv = 1.0f / lt;
        const size_t tok = (size_t)(b * TT + r0 + ni * 16 + lc);
        #pragma unroll
        for (int mi = 0; mi < 4; ++mi) {
            uint2v pk;
            pk.x = cvtpk(o_acc[mi][ni][0] * inv, o_acc[mi][ni][1] * inv);
            pk.y = cvtpk(o_acc[mi][ni][2] * inv, o_acc[mi][ni][3] * inv);
            *(uint2v*)&out[tok * DD + h * HDIM + mi * 16 + quad * 4] = pk;
        }
    }
}

// ---------------------------------------------------------------------------
extern "C" void kernel_launch(void* const* d_in, const int* in_sizes, int n_in,
                              void* d_out, int out_size, void* d_ws, size_t ws_size,
                              hipStream_t stream) {
    const float* x     = (const float*)d_in[0];   // [B,T,D]
    const float* w_qkv = (const float*)d_in[1];   // [D, 3D]
    const float* w_out = (const float*)d_in[2];   // [D, D]
    float* out = (float*)d_out;                   // [B,T,D] fp32

    unsigned short* ws  = (unsigned short*)d_ws;
    unsigned short* xb  = ws;                                  // 8192*1024 (reused for attn out)
    unsigned short* qkv = xb  + (size_t)BT * DD;               // 8192*3072 (V third unused)
    unsigned short* wqT = qkv + (size_t)BT * N1;               // 3072*1024
    unsigned short* woT = wqT + (size_t)N1 * DD;               // 1024*1024
    unsigned short* vtb = woT + (size_t)DD * DD;               // 4096*2048

    const float QSCALE = 0.18033688011112042f;  // (1/8) * log2(e)

    // 1. fused prep: x->bf16, w_qkv->wqT, w_out->woT (one launch)
    prep<<<6144, 256, 0, stream>>>(x, xb, w_qkv, wqT, w_out, woT);
    // 2. QKV = x @ w_qkv (Q pre-scaled; V written transposed to vtb)
    gemm_qkv<<<dim3(N1 / 192, BT / 256), 256, 0, stream>>>(xb, wqT, qkv, BT, N1, DD, QSCALE, vtb);
    // 3. flash attention (writes over xb); one q-tile per block, long first
    attn_fwd<<<dim3(BB * HH, 16), 256, 0, stream>>>(qkv, vtb, xb);
    // 4. out = attn @ w_out (fp32 out)
    gemm_out<<<dim3(DD / 128, BT / 128), 256, 0, stream>>>(xb, woT, out, BT, DD, DD);
}